// Round 1
// baseline (2949.301 us; speedup 1.0000x reference)
//
#include <hip/hip_runtime.h>

// ClDiceLoss for (B=2, C=1, 192,192,192) fp32 volumes.
// soft_skeletonize x5: cross-min (7pt) -> max27 -> contour subtract.

constexpr int D = 192, H = 192, W = 192, B = 2;
constexpr int HW = H * W;                 // 36864
constexpr int VOL = D * H * W;            // 7,077,888
constexpr int NTOT = VOL * B;             // 14,155,776  (fits in int)

// ---------------------------------------------------------------------------
// Kernel A: M = min over 7-point cross of x (per-volume, clamped boundaries)
// block = 256 threads mapped as 64(W) x 4(H); grid = (3, 48, 384)
// ---------------------------------------------------------------------------
__global__ void cross_min_kernel(const float* __restrict__ x,
                                 float* __restrict__ m) {
    const int wx = blockIdx.x * 64 + (threadIdx.x & 63);
    const int y  = blockIdx.y * 4 + (threadIdx.x >> 6);
    const int zb = blockIdx.z;
    const int z  = zb % D;
    const int b  = zb / D;

    const int idx = ((b * D + z) * H + y) * W + wx;
    float v = x[idx];
    if (wx > 0)     v = fminf(v, x[idx - 1]);
    if (wx < W - 1) v = fminf(v, x[idx + 1]);
    if (y > 0)      v = fminf(v, x[idx - W]);
    if (y < H - 1)  v = fminf(v, x[idx + W]);
    if (z > 0)      v = fminf(v, x[idx - HW]);
    if (z < D - 1)  v = fminf(v, x[idx + HW]);
    m[idx] = v;
}

// ---------------------------------------------------------------------------
// Kernel B: x = relu(x - relu(max27(M) - M))   (in-place on x; M read-only)
// ---------------------------------------------------------------------------
__global__ void contour_sub_kernel(const float* __restrict__ m,
                                   float* __restrict__ x) {
    const int wx = blockIdx.x * 64 + (threadIdx.x & 63);
    const int y  = blockIdx.y * 4 + (threadIdx.x >> 6);
    const int zb = blockIdx.z;
    const int z  = zb % D;
    const int b  = zb / D;

    const int idx = ((b * D + z) * H + y) * W + wx;
    const float center = m[idx];

    float mx = center;
    const int z0 = (z > 0) ? -1 : 0, z1 = (z < D - 1) ? 1 : 0;
    const int y0 = (y > 0) ? -1 : 0, y1 = (y < H - 1) ? 1 : 0;
    const int x0 = (wx > 0) ? -1 : 0, x1 = (wx < W - 1) ? 1 : 0;
    for (int dz = z0; dz <= z1; ++dz) {
        const int zi = idx + dz * HW;
        for (int dy = y0; dy <= y1; ++dy) {
            const int yi = zi + dy * W;
            for (int dx = x0; dx <= x1; ++dx) {
                mx = fmaxf(mx, m[yi + dx]);
            }
        }
    }
    const float contour = fmaxf(mx - center, 0.0f);
    const float xv = x[idx];
    x[idx] = fmaxf(xv - contour, 0.0f);
}

// ---------------------------------------------------------------------------
// Reduction: acc[0] += sum(skel*other), acc[1] += sum(skel)
// ---------------------------------------------------------------------------
__global__ void reduce_kernel(const float* __restrict__ skel,
                              const float* __restrict__ other,
                              double* __restrict__ acc) {
    const int i0     = blockIdx.x * blockDim.x + threadIdx.x;
    const int stride = gridDim.x * blockDim.x;
    float sp = 0.0f, ss = 0.0f;
    for (int i = i0; i < NTOT; i += stride) {
        const float sv = skel[i];
        sp += sv * other[i];
        ss += sv;
    }
    double dp = (double)sp;
    double ds = (double)ss;
    #pragma unroll
    for (int off = 32; off > 0; off >>= 1) {
        dp += __shfl_down(dp, off, 64);
        ds += __shfl_down(ds, off, 64);
    }
    if ((threadIdx.x & 63) == 0) {
        atomicAdd(&acc[0], dp);
        atomicAdd(&acc[1], ds);
    }
}

// ---------------------------------------------------------------------------
// Finalize: cldice from the 4 accumulators.
// acc[0]=sum(skel_t*pred) acc[1]=sum(skel_t) acc[2]=sum(skel_p*target) acc[3]=sum(skel_p)
// ---------------------------------------------------------------------------
__global__ void finalize_kernel(const double* __restrict__ acc,
                                float* __restrict__ out) {
    const double recall = (acc[0] + 1e-12) / (acc[1] + 1e-12);
    const double accv   = (acc[2] + 1e-12) / (acc[3] + 1e-12);
    const double cldice = 2.0 * recall * accv / (recall + accv);
    out[0] = (float)(1.0 - cldice);
}

extern "C" void kernel_launch(void* const* d_in, const int* in_sizes, int n_in,
                              void* d_out, int out_size, void* d_ws, size_t ws_size,
                              hipStream_t stream) {
    const float* pred   = (const float*)d_in[0];
    const float* target = (const float*)d_in[1];
    float* out = (float*)d_out;

    char* ws = (char*)d_ws;
    float*  xbuf = (float*)ws;
    float*  mbuf = (float*)(ws + (size_t)NTOT * sizeof(float));
    double* acc  = (double*)(ws + 2 * (size_t)NTOT * sizeof(float));

    hipMemsetAsync(acc, 0, 4 * sizeof(double), stream);

    const dim3 blk(256, 1, 1);
    const dim3 grd(W / 64, H / 4, D * B);

    // ---- skeleton(target), then recall sums vs pred ----
    hipMemcpyAsync(xbuf, target, (size_t)NTOT * sizeof(float),
                   hipMemcpyDeviceToDevice, stream);
    for (int it = 0; it < 5; ++it) {
        cross_min_kernel<<<grd, blk, 0, stream>>>(xbuf, mbuf);
        contour_sub_kernel<<<grd, blk, 0, stream>>>(mbuf, xbuf);
    }
    reduce_kernel<<<1024, 256, 0, stream>>>(xbuf, pred, acc + 0);

    // ---- skeleton(pred), then acc sums vs target ----
    hipMemcpyAsync(xbuf, pred, (size_t)NTOT * sizeof(float),
                   hipMemcpyDeviceToDevice, stream);
    for (int it = 0; it < 5; ++it) {
        cross_min_kernel<<<grd, blk, 0, stream>>>(xbuf, mbuf);
        contour_sub_kernel<<<grd, blk, 0, stream>>>(mbuf, xbuf);
    }
    reduce_kernel<<<1024, 256, 0, stream>>>(xbuf, target, acc + 2);

    finalize_kernel<<<1, 1, 0, stream>>>(acc, out);
}

// Round 2
// 1194.283 us; speedup vs baseline: 2.4695x; 2.4695x over previous
//
#include <hip/hip_runtime.h>

// ClDiceLoss (B=2, C=1, 192^3) fp32.
// Fused soft-skeletonize iteration: one LDS-tiled z-marching kernel does
// cross-min (7pt) -> in-plane 3x3 max (P) -> z-max of P -> contour subtract.
// max27 is separable: max27(M)[z] = max(P[z-1],P[z],P[z+1]), P = 3x3 in-plane max.
// -inf-padded pooling == clamp-to-edge replication for x->M and M->P windows;
// the z-selection of P planes clamps the PLANE INDEX (phantom replicated
// planes would lack the z-direction min term and be wrong).

constexpr int D = 192, H = 192, W = 192, B = 2;
constexpr int HW = H * W;                 // 36864
constexpr int VOL = D * H * W;            // 7,077,888
constexpr int NTOT = VOL * B;             // 14,155,776
constexpr int TX = 64, TY = 8, CZ = 32;   // tile / z-chunk

__device__ __forceinline__ int slot(int z) { return (z + 8) & 3; }

__global__ __launch_bounds__(256, 4) void fused_iter_kernel(
    const float* __restrict__ src, float* __restrict__ dst) {
  // 4-deep rotating planes. x: halo 2 (12x68, row stride 72); M: halo 1
  // (10x66, stride 68); P: output region (8x64).  Total 32.9 KB -> 4 blk/CU.
  __shared__ float xs[4][12][72];
  __shared__ float ms[4][10][68];
  __shared__ float ps[4][8][64];

  const int tid = threadIdx.x;
  const int x0 = blockIdx.x * TX;
  const int y0 = blockIdx.y * TY;
  const int nchunk = D / CZ;              // 6
  const int chunk = blockIdx.z % nchunk;
  const int b = blockIdx.z / nchunk;
  const int z0 = chunk * CZ;
  const float* vsrc = src + (size_t)b * VOL;
  float* vdst = dst + (size_t)b * VOL;

  auto load_plane = [&](int z) {
    const int zc = min(max(z, 0), D - 1);
    const float* base = vsrc + (size_t)zc * HW;
    float* xp = &xs[slot(z)][0][0];
    for (int i = tid; i < 12 * 68; i += 256) {
      const int r = i / 68;
      const int c = i - r * 68;
      const int gy = min(max(y0 - 2 + r, 0), H - 1);
      const int gx = min(max(x0 - 2 + c, 0), W - 1);
      xp[r * 72 + c] = base[gy * W + gx];
    }
  };

  auto compute_m = [&](int z) {  // M(z) = 7-pt cross min, region 10x66
    const float(*xc)[72] = xs[slot(z)];
    const float(*xm)[72] = xs[slot(z - 1)];
    const float(*xq)[72] = xs[slot(z + 1)];
    float(*mp)[68] = ms[slot(z)];
    for (int i = tid; i < 10 * 66; i += 256) {
      const int r = i / 66;
      const int c = i - r * 66;
      float v = xc[r + 1][c + 1];
      v = fminf(v, xc[r + 1][c]);
      v = fminf(v, xc[r + 1][c + 2]);
      v = fminf(v, xc[r][c + 1]);
      v = fminf(v, xc[r + 2][c + 1]);
      v = fminf(v, xm[r + 1][c + 1]);
      v = fminf(v, xq[r + 1][c + 1]);
      mp[r][c] = v;
    }
  };

  auto compute_p = [&](int z) {  // P(z) = 3x3 in-plane max of M(z), 8x64
    const float(*mp)[68] = ms[slot(z)];
    float(*pp)[64] = ps[slot(z)];
    for (int i = tid; i < TY * TX; i += 256) {
      const int r = i >> 6;
      const int c = i & 63;
      float v = mp[r][c];
      v = fmaxf(v, mp[r][c + 1]);
      v = fmaxf(v, mp[r][c + 2]);
      v = fmaxf(v, mp[r + 1][c]);
      v = fmaxf(v, mp[r + 1][c + 1]);
      v = fmaxf(v, mp[r + 1][c + 2]);
      v = fmaxf(v, mp[r + 2][c]);
      v = fmaxf(v, mp[r + 2][c + 1]);
      v = fmaxf(v, mp[r + 2][c + 2]);
      pp[r][c] = v;
    }
  };

  auto compute_out = [&](int z) {  // out(z) = relu(x - relu(maxz(P) - M))
    float* obase = vdst + (size_t)z * HW;
    for (int i = tid; i < TY * TX; i += 256) {
      const int r = i >> 6;
      const int c = i & 63;
      float p = ps[slot(z)][r][c];
      if (z > 0) p = fmaxf(p, ps[slot(z - 1)][r][c]);       // clamp plane idx
      if (z < D - 1) p = fmaxf(p, ps[slot(z + 1)][r][c]);   // at volume ends
      const float m = ms[slot(z)][r + 1][c + 1];
      const float contour = fmaxf(p - m, 0.0f);
      const float xv = xs[slot(z)][r + 2][c + 2];
      obase[(y0 + r) * W + (x0 + c)] = fmaxf(xv - contour, 0.0f);
    }
  };

  // Prologue: planes z0-2..z0; M,P at z0-1 (phantom planes at volume edge are
  // never read thanks to the plane-index clamp in compute_out).
  load_plane(z0 - 2);
  load_plane(z0 - 1);
  load_plane(z0);
  __syncthreads();
  compute_m(z0 - 1);
  __syncthreads();
  compute_p(z0 - 1);
  __syncthreads();

  // Iteration zc: load x(zc+1), M(zc), P(zc), emit out(zc-1).
  for (int zc = z0; zc <= z0 + CZ; ++zc) {
    load_plane(zc + 1);      // overwrites x(zc-3); out(zc-1) below reads x(zc-1) — no race
    __syncthreads();
    compute_m(zc);
    __syncthreads();
    compute_p(zc);
    __syncthreads();
    if (zc > z0) compute_out(zc - 1);
    // no 4th sync needed: next load writes xs slot (zc+2)&3, out reads (zc-1)&3
  }
}

// ---------------------------------------------------------------------------
// Reduction: acc[0] += sum(skel*other), acc[1] += sum(skel)   (float4 loads)
// ---------------------------------------------------------------------------
__global__ void reduce_kernel(const float* __restrict__ skel,
                              const float* __restrict__ other,
                              double* __restrict__ acc) {
  const int i0 = blockIdx.x * blockDim.x + threadIdx.x;
  const int stride = gridDim.x * blockDim.x;
  const float4* s4 = (const float4*)skel;
  const float4* o4 = (const float4*)other;
  const int n4 = NTOT / 4;
  float sp = 0.0f, ss = 0.0f;
  for (int i = i0; i < n4; i += stride) {
    const float4 s = s4[i];
    const float4 o = o4[i];
    sp += s.x * o.x + s.y * o.y + s.z * o.z + s.w * o.w;
    ss += s.x + s.y + s.z + s.w;
  }
  double dp = (double)sp;
  double ds = (double)ss;
#pragma unroll
  for (int off = 32; off > 0; off >>= 1) {
    dp += __shfl_down(dp, off, 64);
    ds += __shfl_down(ds, off, 64);
  }
  if ((threadIdx.x & 63) == 0) {
    atomicAdd(&acc[0], dp);
    atomicAdd(&acc[1], ds);
  }
}

__global__ void finalize_kernel(const double* __restrict__ acc,
                                float* __restrict__ out) {
  const double recall = (acc[0] + 1e-12) / (acc[1] + 1e-12);
  const double accv = (acc[2] + 1e-12) / (acc[3] + 1e-12);
  const double cldice = 2.0 * recall * accv / (recall + accv);
  out[0] = (float)(1.0 - cldice);
}

extern "C" void kernel_launch(void* const* d_in, const int* in_sizes, int n_in,
                              void* d_out, int out_size, void* d_ws, size_t ws_size,
                              hipStream_t stream) {
  const float* pred = (const float*)d_in[0];
  const float* target = (const float*)d_in[1];
  float* out = (float*)d_out;

  float* b0 = (float*)d_ws;
  float* b1 = b0 + NTOT;
  double* acc = (double*)(b1 + NTOT);

  hipMemsetAsync(acc, 0, 4 * sizeof(double), stream);

  const dim3 blk(256, 1, 1);
  const dim3 grd(W / TX, H / TY, (D / CZ) * B);  // 3 x 24 x 12 = 864 blocks

  // skeleton(target): in -> b0 -> b1 -> b0 -> b1 -> b0
  fused_iter_kernel<<<grd, blk, 0, stream>>>(target, b0);
  fused_iter_kernel<<<grd, blk, 0, stream>>>(b0, b1);
  fused_iter_kernel<<<grd, blk, 0, stream>>>(b1, b0);
  fused_iter_kernel<<<grd, blk, 0, stream>>>(b0, b1);
  fused_iter_kernel<<<grd, blk, 0, stream>>>(b1, b0);
  reduce_kernel<<<1024, 256, 0, stream>>>(b0, pred, acc + 0);

  // skeleton(pred)
  fused_iter_kernel<<<grd, blk, 0, stream>>>(pred, b0);
  fused_iter_kernel<<<grd, blk, 0, stream>>>(b0, b1);
  fused_iter_kernel<<<grd, blk, 0, stream>>>(b1, b0);
  fused_iter_kernel<<<grd, blk, 0, stream>>>(b0, b1);
  fused_iter_kernel<<<grd, blk, 0, stream>>>(b1, b0);
  reduce_kernel<<<1024, 256, 0, stream>>>(b0, target, acc + 2);

  finalize_kernel<<<1, 1, 0, stream>>>(acc, out);
}

// Round 3
// 878.503 us; speedup vs baseline: 3.3572x; 1.3595x over previous
//
#include <hip/hip_runtime.h>
#include <cfloat>

// ClDiceLoss (B=2, C=1, 192^3) fp32.
// soft_skeletonize iteration, fully fused & separable:
//   M = 7-pt cross min (clamped loads: duplicates are harmless for min)
//   R = max3 over x of M   (computed by the SAME wave that wrote M's row ->
//                           same-wave LDS RAW is HW-ordered, no barrier)
//   P = max3 over y of R   (registers; z-max of P via per-cell register rotation)
//   out = relu(x - relu(max(P[z-1],P[z],P[z+1]) - M))
// Boundary: the 27-max must NOT see phantom cells -> M at out-of-range (y,x)
// is written as -FLT_MAX (exact -inf-pad reduce_window semantics); z handled
// by plane-index guards.
// Last iteration per chain fuses the reduction (sum skel*other, sum skel)
// instead of storing the skeleton.

constexpr int D = 192, H = 192, W = 192, B = 2;
constexpr int HW = H * W;
constexpr int VOL = D * HW;
constexpr int TX = 64, TY = 8, CZ = 24;
constexpr int NCH = D / CZ;                    // 8 chunks
constexpr int NPART = 3 * 24 * NCH * B;        // 1152 blocks per dispatch

__device__ __forceinline__ int slot3(int z) { return (z + 384) % 3; }

__global__ __launch_bounds__(256, 6) void skel_iter(
    const float* __restrict__ src, float* __restrict__ dst,
    const float* __restrict__ oth, double* __restrict__ part, int last) {
  __shared__ float xs[3][12][72];   // x planes z-1,z,z+1; halo 2; 10.1 KB
  __shared__ float ms[10][68];      // M plane, halo 1 (rows y0-1..y0+8)
  __shared__ float rs[10][64];      // R plane (rows y0-1..y0+8)
  __shared__ double red[8];

  const int tid = threadIdx.x;
  const int wave = tid >> 6;
  const int lane = tid & 63;
  const int x0 = blockIdx.x * TX;
  const int y0 = blockIdx.y * TY;
  const int chunk = blockIdx.z % NCH;
  const int b = blockIdx.z / NCH;
  const int z0 = chunk * CZ;
  const float* vs = src + (size_t)b * VOL;
  float* vd = dst + (size_t)b * VOL;
  const float* vo = oth + (size_t)b * VOL;

  auto load_x = [&](int z) {
    const int zc = min(max(z, 0), D - 1);
    const float* base = vs + (size_t)zc * HW;
    float* xp = &xs[slot3(z)][0][0];
    for (int i = tid; i < 12 * 68; i += 256) {
      const int r = i / 68;
      const int c = i - r * 68;
      const int gy = min(max(y0 - 2 + r, 0), H - 1);
      const int gx = min(max(x0 - 2 + c, 0), W - 1);
      xp[r * 72 + c] = base[gy * W + gx];
    }
  };

  // M rows + R rows for this wave: rows wave, wave+4, wave+8(<10).
  auto mr_stage = [&](int z) {
    const float(*xc)[72] = xs[slot3(z)];
    const float(*xm)[72] = xs[slot3(z - 1)];
    const float(*xq)[72] = xs[slot3(z + 1)];
    for (int r = wave; r < 10; r += 4) {
      const int gy = y0 - 1 + r;
      {
        const int c = lane;
        const int gx = x0 - 1 + c;
        float v = fminf(xc[r + 1][c + 1], fminf(xc[r + 1][c], xc[r + 1][c + 2]));
        v = fminf(v, fminf(xc[r][c + 1], xc[r + 2][c + 1]));
        v = fminf(v, fminf(xm[r + 1][c + 1], xq[r + 1][c + 1]));
        ms[r][c] = ((unsigned)gy < (unsigned)H && (unsigned)gx < (unsigned)W)
                       ? v : -FLT_MAX;
      }
      if (lane < 2) {
        const int c = 64 + lane;
        const int gx = x0 - 1 + c;
        float v = fminf(xc[r + 1][c + 1], fminf(xc[r + 1][c], xc[r + 1][c + 2]));
        v = fminf(v, fminf(xc[r][c + 1], xc[r + 2][c + 1]));
        v = fminf(v, fminf(xm[r + 1][c + 1], xq[r + 1][c + 1]));
        ms[r][c] = ((unsigned)gy < (unsigned)H && (unsigned)gx < (unsigned)W)
                       ? v : -FLT_MAX;
      }
      // R row r: reads ms row r just written by THIS wave (in-order DS ops).
      rs[r][lane] = fmaxf(fmaxf(ms[r][lane], ms[r][lane + 1]), ms[r][lane + 2]);
    }
  };

  // Per-thread out cells: (row = wave + 4k, col = lane), k = 0,1.
  float p_mm[2] = {0, 0}, p_m[2] = {0, 0};
  float m_prev[2] = {0, 0}, x_prev[2] = {0, 0};
  float sp = 0.0f, ss = 0.0f;

  auto pout_stage = [&](int zc, bool emit) {
    #pragma unroll
    for (int k = 0; k < 2; ++k) {
      const int ro = wave + 4 * k;
      const float pc =
          fmaxf(fmaxf(rs[ro][lane], rs[ro + 1][lane]), rs[ro + 2][lane]);
      const float mc = ms[ro + 1][lane + 1];
      const float xc = xs[slot3(zc)][ro + 2][lane + 2];
      if (emit) {
        const int zo = zc - 1;
        float p = p_m[k];
        if (zo > 0) p = fmaxf(p, p_mm[k]);
        if (zo < D - 1) p = fmaxf(p, pc);
        const float contour = fmaxf(p - m_prev[k], 0.0f);
        const float o = fmaxf(x_prev[k] - contour, 0.0f);
        const size_t g = (size_t)zo * HW + (size_t)(y0 + ro) * W + (x0 + lane);
        if (last) {
          sp += o * vo[g];
          ss += o;
        } else {
          vd[g] = o;
        }
      }
      p_mm[k] = p_m[k];
      p_m[k] = pc;
      m_prev[k] = mc;
      x_prev[k] = xc;
    }
  };

  // Prologue: planes z0-2..z0; M/R/P at z0-1 seed the register pipeline.
  load_x(z0 - 2);
  load_x(z0 - 1);
  load_x(z0);
  __syncthreads();
  mr_stage(z0 - 1);
  __syncthreads();
  pout_stage(z0 - 1, false);

  for (int zc = z0; zc <= z0 + CZ; ++zc) {
    load_x(zc + 1);
    __syncthreads();   // xs(zc+1) visible; guards ms/rs overwrite vs prior reads
    mr_stage(zc);
    __syncthreads();   // ms/rs visible to all waves
    pout_stage(zc, zc > z0);
  }

  if (last) {
    #pragma unroll
    for (int off = 32; off > 0; off >>= 1) {
      sp += __shfl_down(sp, off, 64);
      ss += __shfl_down(ss, off, 64);
    }
    if (lane == 0) {
      red[wave] = (double)sp;
      red[4 + wave] = (double)ss;
    }
    __syncthreads();
    if (tid == 0) {
      const double a = red[0] + red[1] + red[2] + red[3];
      const double s = red[4] + red[5] + red[6] + red[7];
      const int lin =
          ((b * NCH + chunk) * 24 + blockIdx.y) * 3 + blockIdx.x;  // 0..1151
      part[2 * lin] = a;
      part[2 * lin + 1] = s;
    }
  }
}

__global__ void finalize_kernel(const double* __restrict__ pa,
                                const double* __restrict__ pb,
                                float* __restrict__ out) {
  __shared__ double red[4][4];
  double s[4] = {0, 0, 0, 0};
  for (int i = threadIdx.x; i < NPART; i += 256) {
    s[0] += pa[2 * i];
    s[1] += pa[2 * i + 1];
    s[2] += pb[2 * i];
    s[3] += pb[2 * i + 1];
  }
  #pragma unroll
  for (int off = 32; off > 0; off >>= 1)
    #pragma unroll
    for (int j = 0; j < 4; ++j) s[j] += __shfl_down(s[j], off, 64);
  const int wave = threadIdx.x >> 6, lane = threadIdx.x & 63;
  if (lane == 0)
    for (int j = 0; j < 4; ++j) red[j][wave] = s[j];
  __syncthreads();
  if (threadIdx.x == 0) {
    double t[4];
    for (int j = 0; j < 4; ++j)
      t[j] = red[j][0] + red[j][1] + red[j][2] + red[j][3];
    const double recall = (t[0] + 1e-12) / (t[1] + 1e-12);
    const double accv = (t[2] + 1e-12) / (t[3] + 1e-12);
    const double cldice = 2.0 * recall * accv / (recall + accv);
    out[0] = (float)(1.0 - cldice);
  }
}

extern "C" void kernel_launch(void* const* d_in, const int* in_sizes, int n_in,
                              void* d_out, int out_size, void* d_ws, size_t ws_size,
                              hipStream_t stream) {
  const float* pred = (const float*)d_in[0];
  const float* target = (const float*)d_in[1];
  float* out = (float*)d_out;

  const size_t NTOT = (size_t)VOL * B;
  float* b0 = (float*)d_ws;
  float* b1 = b0 + NTOT;
  double* partA = (double*)(b1 + NTOT);
  double* partB = partA + 2 * NPART;

  const dim3 blk(256, 1, 1);
  const dim3 grd(W / TX, H / TY, NCH * B);  // 3 x 24 x 16 = 1152 blocks

  // chain A: skeleton(target), fused reduce vs pred -> partA
  skel_iter<<<grd, blk, 0, stream>>>(target, b0, target, partA, 0);
  skel_iter<<<grd, blk, 0, stream>>>(b0, b1, target, partA, 0);
  skel_iter<<<grd, blk, 0, stream>>>(b1, b0, target, partA, 0);
  skel_iter<<<grd, blk, 0, stream>>>(b0, b1, target, partA, 0);
  skel_iter<<<grd, blk, 0, stream>>>(b1, b0, pred, partA, 1);

  // chain B: skeleton(pred), fused reduce vs target -> partB
  skel_iter<<<grd, blk, 0, stream>>>(pred, b0, pred, partB, 0);
  skel_iter<<<grd, blk, 0, stream>>>(b0, b1, pred, partB, 0);
  skel_iter<<<grd, blk, 0, stream>>>(b1, b0, pred, partB, 0);
  skel_iter<<<grd, blk, 0, stream>>>(b0, b1, pred, partB, 0);
  skel_iter<<<grd, blk, 0, stream>>>(b1, b0, target, partB, 1);

  finalize_kernel<<<1, 256, 0, stream>>>(partA, partB, out);
}

// Round 4
// 822.448 us; speedup vs baseline: 3.5860x; 1.0682x over previous
//
#include <hip/hip_runtime.h>
#include <cfloat>

// ClDiceLoss (B=2, C=1, 192^3) fp32.
// Fused soft-skeletonize iteration, 1-barrier software pipeline per z-plane:
//   step s (z = z0+s):  barrier;
//     LD : load x(z+1)          -> xs slot (z+1)&3     (4-slot rotation)
//     MR : M,R at plane (z-1)   -> ms/rs slot (z-1)&1  (M=7pt cross-min,
//          R=max3_x(M); R computed by the SAME wave that wrote M's row ->
//          in-order DS, no extra barrier)
//     PO : P(z-2)=max3_y(R); emit out(z-3) from register history
//          out = relu(x - relu(max(P[zo-1],P[zo],P[zo+1]) - M))
// Phases are mutually independent within a step -> global loads overlap LDS.
// Boundary: M at out-of-volume (y,x) = -FLT_MAX (exact -inf-pad semantics);
// z edges via plane-index guards; clamped duplicate loads are harmless for min.
// Both chains (skel(target), skel(pred)) run in ONE dispatch when ws allows.
// Last iteration fuses the two reductions instead of storing the skeleton.

constexpr int D = 192, H = 192, W = 192, B = 2;
constexpr int HW = H * W;
constexpr int VOL = D * HW;
constexpr int TX = 64, TY = 8;
constexpr int MAXPART = 3 * 24 * 8 * B;   // worst-case blocks per chain (cz=24)

__global__ __launch_bounds__(256, 4) void skel_iter(
    const float* __restrict__ srcA, float* __restrict__ dstA,
    const float* __restrict__ othA, double* __restrict__ partA,
    const float* __restrict__ srcB, float* __restrict__ dstB,
    const float* __restrict__ othB, double* __restrict__ partB,
    int cz, int nch, int last) {
  __shared__ float xs[4][12][72];   // x planes, halo 2, 13.8 KB
  __shared__ float ms[2][10][68];   // M parity planes, halo 1
  __shared__ float rs[2][10][64];   // R parity planes
  __shared__ double red[8];

  const int tid = threadIdx.x;
  const int wave = tid >> 6;
  const int lane = tid & 63;
  const int x0 = blockIdx.x * TX;
  const int y0 = blockIdx.y * TY;
  int t = blockIdx.z;
  const int chunk = t % nch; t /= nch;
  const int b = t % B;
  const int chain = t / B;
  const int z0 = chunk * cz;

  const float* vs = (chain ? srcB : srcA) + (size_t)b * VOL;
  float* vd = (chain ? dstB : dstA) + (size_t)b * VOL;
  const float* vo = (chain ? othB : othA) + (size_t)b * VOL;
  double* part = chain ? partB : partA;

  // ---- hoisted geometry (z-invariant) ----
  // LD: rows r = wave*3+j (12 rows), cols c=lane (+ c=64+lane for lane<4)
  int yoff[3], lidx[3];
  #pragma unroll
  for (int j = 0; j < 3; ++j) {
    const int r = wave * 3 + j;
    yoff[j] = min(max(y0 - 2 + r, 0), H - 1) * W;
    lidx[j] = r * 72;
  }
  const int gxA = min(max(x0 - 2 + lane, 0), W - 1);
  const int gxB = min(max(x0 + 62 + lane, 0), W - 1);
  // MR masks: M col c=lane -> gx = x0-1+lane ; extra c=64+lane -> x0+63+lane
  const bool xokA = ((unsigned)(x0 - 1 + lane) < (unsigned)W);
  const bool xokB = ((unsigned)(x0 + 63 + lane) < (unsigned)W);
  // PO: per-thread out cells rows ro = wave+4k
  const int ooff0 = (y0 + wave) * W + (x0 + lane);
  const int ooff1 = (y0 + wave + 4) * W + (x0 + lane);

  auto load_x = [&](int z) {
    const int zc = min(max(z, 0), D - 1);
    const float* base = vs + (size_t)zc * HW;
    float* xp = &xs[(z + 1024) & 3][0][0];
    #pragma unroll
    for (int j = 0; j < 3; ++j) {
      xp[lidx[j] + lane] = base[yoff[j] + gxA];
      if (lane < 4) xp[lidx[j] + 64 + lane] = base[yoff[j] + gxB];
    }
  };

  auto mr_stage = [&](int z) {
    const float(*xc)[72] = xs[(z + 1024) & 3];
    const float(*xm)[72] = xs[(z + 1023) & 3];
    const float(*xq)[72] = xs[(z + 1025) & 3];
    const int par = (z + 1024) & 1;
    #pragma unroll
    for (int i = 0; i < 3; ++i) {
      if (i == 2 && wave >= 2) break;          // rows 8,9 -> waves 0,1 only
      const int r = wave + 4 * i;
      const bool rok = ((unsigned)(y0 - 1 + r) < (unsigned)H);
      {
        const int c = lane;
        float v = fminf(xc[r + 1][c + 1], fminf(xc[r + 1][c], xc[r + 1][c + 2]));
        v = fminf(v, fminf(xc[r][c + 1], xc[r + 2][c + 1]));
        v = fminf(v, fminf(xm[r + 1][c + 1], xq[r + 1][c + 1]));
        ms[par][r][c] = (rok && xokA) ? v : -FLT_MAX;
      }
      if (lane < 2) {
        const int c = 64 + lane;
        float v = fminf(xc[r + 1][c + 1], fminf(xc[r + 1][c], xc[r + 1][c + 2]));
        v = fminf(v, fminf(xc[r][c + 1], xc[r + 2][c + 1]));
        v = fminf(v, fminf(xm[r + 1][c + 1], xq[r + 1][c + 1]));
        ms[par][r][c] = (rok && xokB) ? v : -FLT_MAX;
      }
      // same-wave RAW on ms row r (in-order DS ops)
      rs[par][r][lane] =
          fmaxf(fmaxf(ms[par][r][lane], ms[par][r][lane + 1]), ms[par][r][lane + 2]);
    }
  };

  float p_mm[2], p_m[2], m_prev[2], x_prev[2];
  float sp = 0.0f, ss = 0.0f;

  auto po_stage = [&](int z2, bool emit, int zo) {  // z2 = z-2, zo = z-3
    const int par = (z2 + 1024) & 1;
    const float(*xp)[72] = xs[(z2 + 1024) & 3];
    #pragma unroll
    for (int k = 0; k < 2; ++k) {
      const int ro = wave + 4 * k;
      const float pc =
          fmaxf(fmaxf(rs[par][ro][lane], rs[par][ro + 1][lane]), rs[par][ro + 2][lane]);
      const float mc = ms[par][ro + 1][lane + 1];
      const float xv = xp[ro + 2][lane + 2];
      if (emit) {
        float p = p_m[k];
        if (zo > 0) p = fmaxf(p, p_mm[k]);
        if (zo < D - 1) p = fmaxf(p, pc);
        const float contour = fmaxf(p - m_prev[k], 0.0f);
        const float o = fmaxf(x_prev[k] - contour, 0.0f);
        const size_t g = (size_t)zo * HW + (k ? ooff1 : ooff0);
        if (last) {
          sp += o * vo[g];
          ss += o;
        } else {
          vd[g] = o;
        }
      }
      p_mm[k] = p_m[k];
      p_m[k] = pc;
      m_prev[k] = mc;
      x_prev[k] = xv;
    }
  };

  load_x(z0 - 2);
  load_x(z0 - 1);
  load_x(z0);
  for (int s = 0; s <= cz + 2; ++s) {
    __syncthreads();
    const int z = z0 + s;
    if (s <= cz) load_x(z + 1);
    if (s <= cz + 1) mr_stage(z - 1);
    if (s >= 1) po_stage(z - 2, s >= 3, z - 3);
  }

  if (last) {
    #pragma unroll
    for (int off = 32; off > 0; off >>= 1) {
      sp += __shfl_down(sp, off, 64);
      ss += __shfl_down(ss, off, 64);
    }
    if (lane == 0) {
      red[wave] = (double)sp;
      red[4 + wave] = (double)ss;
    }
    __syncthreads();
    if (tid == 0) {
      const double a = red[0] + red[1] + red[2] + red[3];
      const double s2 = red[4] + red[5] + red[6] + red[7];
      const int lin = ((b * nch + chunk) * 24 + blockIdx.y) * 3 + blockIdx.x;
      part[2 * lin] = a;
      part[2 * lin + 1] = s2;
    }
  }
}

__global__ void finalize_kernel(const double* __restrict__ pa,
                                const double* __restrict__ pb,
                                float* __restrict__ out, int npart) {
  __shared__ double red[4][4];
  double s[4] = {0, 0, 0, 0};
  for (int i = threadIdx.x; i < npart; i += 256) {
    s[0] += pa[2 * i];
    s[1] += pa[2 * i + 1];
    s[2] += pb[2 * i];
    s[3] += pb[2 * i + 1];
  }
  #pragma unroll
  for (int off = 32; off > 0; off >>= 1)
    #pragma unroll
    for (int j = 0; j < 4; ++j) s[j] += __shfl_down(s[j], off, 64);
  const int wave = threadIdx.x >> 6, lane = threadIdx.x & 63;
  if (lane == 0)
    for (int j = 0; j < 4; ++j) red[j][wave] = s[j];
  __syncthreads();
  if (threadIdx.x == 0) {
    double t[4];
    for (int j = 0; j < 4; ++j)
      t[j] = red[j][0] + red[j][1] + red[j][2] + red[j][3];
    const double recall = (t[0] + 1e-12) / (t[1] + 1e-12);
    const double accv = (t[2] + 1e-12) / (t[3] + 1e-12);
    const double cldice = 2.0 * recall * accv / (recall + accv);
    out[0] = (float)(1.0 - cldice);
  }
}

extern "C" void kernel_launch(void* const* d_in, const int* in_sizes, int n_in,
                              void* d_out, int out_size, void* d_ws, size_t ws_size,
                              hipStream_t stream) {
  const float* pred = (const float*)d_in[0];
  const float* target = (const float*)d_in[1];
  float* out = (float*)d_out;
  const size_t NT = (size_t)VOL * B;

  const size_t need_merged = 4 * NT * sizeof(float) + 4 * MAXPART * sizeof(double);
  const dim3 blk(256, 1, 1);

  if (ws_size >= need_merged) {
    // Both chains per dispatch: 5 stencil dispatches + finalize.
    float* a0 = (float*)d_ws;
    float* a1 = a0 + NT;
    float* c0 = a1 + NT;
    float* c1 = c0 + NT;
    double* pA = (double*)(c1 + NT);
    double* pB = pA + 2 * MAXPART;
    const int cz = 48, nch = 4;
    const int npart = 3 * 24 * nch * B;             // 576 per chain
    const dim3 grd(3, 24, nch * B * 2);             // 1152 blocks
    skel_iter<<<grd, blk, 0, stream>>>(target, a0, pred, pA, pred, c0, target, pB, cz, nch, 0);
    skel_iter<<<grd, blk, 0, stream>>>(a0, a1, pred, pA, c0, c1, target, pB, cz, nch, 0);
    skel_iter<<<grd, blk, 0, stream>>>(a1, a0, pred, pA, c1, c0, target, pB, cz, nch, 0);
    skel_iter<<<grd, blk, 0, stream>>>(a0, a1, pred, pA, c0, c1, target, pB, cz, nch, 0);
    skel_iter<<<grd, blk, 0, stream>>>(a1, a0, pred, pA, c1, c0, target, pB, cz, nch, 1);
    finalize_kernel<<<1, 256, 0, stream>>>(pA, pB, out, npart);
  } else {
    // Fallback: 2 buffers, chains sequential (chain bit always 0).
    float* b0 = (float*)d_ws;
    float* b1 = b0 + NT;
    double* pA = (double*)(b1 + NT);
    double* pB = pA + 2 * MAXPART;
    const int cz = 24, nch = 8;
    const int npart = 3 * 24 * nch * B;             // 1152
    const dim3 grd(3, 24, nch * B);
    skel_iter<<<grd, blk, 0, stream>>>(target, b0, pred, pA, nullptr, nullptr, nullptr, nullptr, cz, nch, 0);
    skel_iter<<<grd, blk, 0, stream>>>(b0, b1, pred, pA, nullptr, nullptr, nullptr, nullptr, cz, nch, 0);
    skel_iter<<<grd, blk, 0, stream>>>(b1, b0, pred, pA, nullptr, nullptr, nullptr, nullptr, cz, nch, 0);
    skel_iter<<<grd, blk, 0, stream>>>(b0, b1, pred, pA, nullptr, nullptr, nullptr, nullptr, cz, nch, 0);
    skel_iter<<<grd, blk, 0, stream>>>(b1, b0, pred, pA, nullptr, nullptr, nullptr, nullptr, cz, nch, 1);
    skel_iter<<<grd, blk, 0, stream>>>(pred, b0, target, pB, nullptr, nullptr, nullptr, nullptr, cz, nch, 0);
    skel_iter<<<grd, blk, 0, stream>>>(b0, b1, target, pB, nullptr, nullptr, nullptr, nullptr, cz, nch, 0);
    skel_iter<<<grd, blk, 0, stream>>>(b1, b0, target, pB, nullptr, nullptr, nullptr, nullptr, cz, nch, 0);
    skel_iter<<<grd, blk, 0, stream>>>(b0, b1, target, pB, nullptr, nullptr, nullptr, nullptr, cz, nch, 0);
    skel_iter<<<grd, blk, 0, stream>>>(b1, b0, target, pB, nullptr, nullptr, nullptr, nullptr, cz, nch, 1);
    finalize_kernel<<<1, 256, 0, stream>>>(pA, pB, out, npart);
  }
}

// Round 5
// 677.623 us; speedup vs baseline: 4.3524x; 1.2137x over previous
//
#include <hip/hip_runtime.h>
#include <cfloat>

// ClDiceLoss (B=2, C=1, 192^3) fp32.
// Fused soft-skeletonize iteration, 1-barrier-per-plane pipeline:
//   step s (z = z0+s):
//     A: load x(z+1) -> xs[(z+1)&3]; M(z-1) = 7pt cross-min -> ms[(z-1)%3];
//        grab own-cell x(z-1) into registers.
//     barrier
//     B: P(z-1) = 3x3 in-plane max of M(z-1) (9 LDS reads, no intermediate);
//        emit out(z-2) = relu(x - relu(max(P(z-3),P(z-2),P(z-1)) - M(z-2)))
//        from register history (mc via 2 LDS reads of ms[(z-2)%3]).
// Slot disjointness (xs 4-deep, ms 3-deep) makes A(s+1) race-free against
// B(s) without a second barrier. Boundary: M at out-of-volume (y,x) = -FLT_MAX
// (exact -inf-pad reduce_window semantics); z edges via plane-index guards;
// clamped duplicate loads harmless for min.
// Both chains (skel(target), skel(pred)) in one dispatch when ws allows; the
// 5th iteration fuses the reductions instead of storing the skeleton.

constexpr int D = 192, H = 192, W = 192, B = 2;
constexpr int HW = H * W;
constexpr int VOL = D * HW;
constexpr int TX = 64, TY = 8;
constexpr int CZ = 32, NCH = 6;
constexpr int MAXPART = 3 * 24 * NCH * B;   // 864 blocks per chain

__device__ __forceinline__ int slot3(int z) { return (z + 3072) % 3; }

__global__ __launch_bounds__(256, 7) void skel_iter(
    const float* __restrict__ srcA, float* __restrict__ dstA,
    const float* __restrict__ othA, double* __restrict__ partA,
    const float* __restrict__ srcB, float* __restrict__ dstB,
    const float* __restrict__ othB, double* __restrict__ partB,
    int cz, int nch, int last) {
  __shared__ float xs[4][12][72];   // x planes, halo 2 (13.8 KB)
  __shared__ float ms[3][10][68];   // M planes, halo 1, 3-deep (8.2 KB)
  __shared__ double red[8];

  const int tid = threadIdx.x;
  const int wave = tid >> 6;
  const int lane = tid & 63;
  const int x0 = blockIdx.x * TX;
  const int y0 = blockIdx.y * TY;
  int t = blockIdx.z;
  const int chunk = t % nch; t /= nch;
  const int b = t % B;
  const int chain = t / B;
  const int z0 = chunk * cz;

  const float* vs = (chain ? srcB : srcA) + (size_t)b * VOL;
  float* vd = (chain ? dstB : dstA) + (size_t)b * VOL;
  const float* vo = (chain ? othB : othA) + (size_t)b * VOL;
  double* part = chain ? partB : partA;

  // ---- hoisted z-invariant geometry ----
  int yoff[3], lidx[3];
  #pragma unroll
  for (int j = 0; j < 3; ++j) {
    const int r = wave * 3 + j;               // 12 halo rows
    yoff[j] = min(max(y0 - 2 + r, 0), H - 1) * W;
    lidx[j] = r * 72;
  }
  const int gxA = min(max(x0 - 2 + lane, 0), W - 1);
  const int gxB = min(max(x0 + 62 + lane, 0), W - 1);
  const bool xokA = ((unsigned)(x0 - 1 + lane) < (unsigned)W);
  const bool xokB = ((unsigned)(x0 + 63 + lane) < (unsigned)W);
  const int ooff0 = (y0 + wave) * W + (x0 + lane);
  const int ooff1 = (y0 + wave + 4) * W + (x0 + lane);

  auto load_x = [&](int z) {
    const int zc = min(max(z, 0), D - 1);
    const float* base = vs + (size_t)zc * HW;
    float* xp = &xs[(z + 1024) & 3][0][0];
    #pragma unroll
    for (int j = 0; j < 3; ++j) {
      xp[lidx[j] + lane] = base[yoff[j] + gxA];
      if (lane < 4) xp[lidx[j] + 64 + lane] = base[yoff[j] + gxB];
    }
  };

  auto m_stage = [&](int z) {   // M(z) -> ms[slot3(z)]
    const float(*xc)[72] = xs[(z + 1024) & 3];
    const float(*xm)[72] = xs[(z + 1023) & 3];
    const float(*xq)[72] = xs[(z + 1025) & 3];
    float(*mp)[68] = ms[slot3(z)];
    #pragma unroll
    for (int i = 0; i < 3; ++i) {
      if (i == 2 && wave >= 2) break;         // rows 8,9 -> waves 0,1
      const int r = wave + 4 * i;
      const bool rok = ((unsigned)(y0 - 1 + r) < (unsigned)H);
      {
        const int c = lane;
        float v = fminf(xc[r + 1][c + 1], fminf(xc[r + 1][c], xc[r + 1][c + 2]));
        v = fminf(v, fminf(xc[r][c + 1], xc[r + 2][c + 1]));
        v = fminf(v, fminf(xm[r + 1][c + 1], xq[r + 1][c + 1]));
        mp[r][c] = (rok && xokA) ? v : -FLT_MAX;
      }
      if (lane < 2) {
        const int c = 64 + lane;
        float v = fminf(xc[r + 1][c + 1], fminf(xc[r + 1][c], xc[r + 1][c + 2]));
        v = fminf(v, fminf(xc[r][c + 1], xc[r + 2][c + 1]));
        v = fminf(v, fminf(xm[r + 1][c + 1], xq[r + 1][c + 1]));
        mp[r][c] = (rok && xokB) ? v : -FLT_MAX;
      }
    }
  };

  float p_mm[2], p_m[2], x_prev[2], x_cur[2];
  float sp = 0.0f, ss = 0.0f;

  // Prologue: planes z0-2..z0.
  load_x(z0 - 2);
  load_x(z0 - 1);
  load_x(z0);
  __syncthreads();

  for (int s = 0; s <= cz + 1; ++s) {
    const int z = z0 + s;
    // ---- phase A ----
    if (s <= cz) load_x(z + 1);
    m_stage(z - 1);
    {
      const float(*xp)[72] = xs[(z + 1023) & 3];   // plane z-1
      x_cur[0] = xp[wave + 2][lane + 2];
      x_cur[1] = xp[wave + 6][lane + 2];
    }
    __syncthreads();
    // ---- phase B ----
    const float(*mp)[68] = ms[slot3(z - 1)];
    const float(*mq)[68] = ms[slot3(z - 2)];
    const int zo = z - 2;
    #pragma unroll
    for (int k = 0; k < 2; ++k) {
      const int ro = wave + 4 * k;
      float pc = fmaxf(fmaxf(mp[ro][lane], mp[ro][lane + 1]), mp[ro][lane + 2]);
      pc = fmaxf(pc, fmaxf(fmaxf(mp[ro + 1][lane], mp[ro + 1][lane + 1]),
                           mp[ro + 1][lane + 2]));
      pc = fmaxf(pc, fmaxf(fmaxf(mp[ro + 2][lane], mp[ro + 2][lane + 1]),
                           mp[ro + 2][lane + 2]));
      if (s >= 2) {
        const float mc = mq[ro + 1][lane + 1];
        float p = p_m[k];
        if (zo > 0) p = fmaxf(p, p_mm[k]);
        if (zo < D - 1) p = fmaxf(p, pc);
        const float contour = fmaxf(p - mc, 0.0f);
        const float o = fmaxf(x_prev[k] - contour, 0.0f);
        const size_t g = (size_t)zo * HW + (k ? ooff1 : ooff0);
        if (last) {
          sp += o * vo[g];
          ss += o;
        } else {
          vd[g] = o;
        }
      }
      p_mm[k] = p_m[k];
      p_m[k] = pc;
      x_prev[k] = x_cur[k];
    }
  }

  if (last) {
    #pragma unroll
    for (int off = 32; off > 0; off >>= 1) {
      sp += __shfl_down(sp, off, 64);
      ss += __shfl_down(ss, off, 64);
    }
    if (lane == 0) {
      red[wave] = (double)sp;
      red[4 + wave] = (double)ss;
    }
    __syncthreads();
    if (tid == 0) {
      const double a = red[0] + red[1] + red[2] + red[3];
      const double s2 = red[4] + red[5] + red[6] + red[7];
      const int lin = ((b * nch + chunk) * 24 + blockIdx.y) * 3 + blockIdx.x;
      part[2 * lin] = a;
      part[2 * lin + 1] = s2;
    }
  }
}

__global__ void finalize_kernel(const double* __restrict__ pa,
                                const double* __restrict__ pb,
                                float* __restrict__ out, int npart) {
  __shared__ double red[4][4];
  double s[4] = {0, 0, 0, 0};
  for (int i = threadIdx.x; i < npart; i += 256) {
    s[0] += pa[2 * i];
    s[1] += pa[2 * i + 1];
    s[2] += pb[2 * i];
    s[3] += pb[2 * i + 1];
  }
  #pragma unroll
  for (int off = 32; off > 0; off >>= 1)
    #pragma unroll
    for (int j = 0; j < 4; ++j) s[j] += __shfl_down(s[j], off, 64);
  const int wave = threadIdx.x >> 6, lane = threadIdx.x & 63;
  if (lane == 0)
    for (int j = 0; j < 4; ++j) red[j][wave] = s[j];
  __syncthreads();
  if (threadIdx.x == 0) {
    double t[4];
    for (int j = 0; j < 4; ++j)
      t[j] = red[j][0] + red[j][1] + red[j][2] + red[j][3];
    const double recall = (t[0] + 1e-12) / (t[1] + 1e-12);
    const double accv = (t[2] + 1e-12) / (t[3] + 1e-12);
    const double cldice = 2.0 * recall * accv / (recall + accv);
    out[0] = (float)(1.0 - cldice);
  }
}

extern "C" void kernel_launch(void* const* d_in, const int* in_sizes, int n_in,
                              void* d_out, int out_size, void* d_ws, size_t ws_size,
                              hipStream_t stream) {
  const float* pred = (const float*)d_in[0];
  const float* target = (const float*)d_in[1];
  float* out = (float*)d_out;
  const size_t NT = (size_t)VOL * B;

  const size_t need_merged = 4 * NT * sizeof(float) + 4 * MAXPART * sizeof(double);
  const dim3 blk(256, 1, 1);
  const int cz = CZ, nch = NCH;
  const int npart = 3 * 24 * nch * B;   // 864 per chain

  if (ws_size >= need_merged) {
    float* a0 = (float*)d_ws;
    float* a1 = a0 + NT;
    float* c0 = a1 + NT;
    float* c1 = c0 + NT;
    double* pA = (double*)(c1 + NT);
    double* pB = pA + 2 * MAXPART;
    const dim3 grd(3, 24, nch * B * 2);   // 1728 blocks
    skel_iter<<<grd, blk, 0, stream>>>(target, a0, pred, pA, pred, c0, target, pB, cz, nch, 0);
    skel_iter<<<grd, blk, 0, stream>>>(a0, a1, pred, pA, c0, c1, target, pB, cz, nch, 0);
    skel_iter<<<grd, blk, 0, stream>>>(a1, a0, pred, pA, c1, c0, target, pB, cz, nch, 0);
    skel_iter<<<grd, blk, 0, stream>>>(a0, a1, pred, pA, c0, c1, target, pB, cz, nch, 0);
    skel_iter<<<grd, blk, 0, stream>>>(a1, a0, pred, pA, c1, c0, target, pB, cz, nch, 1);
    finalize_kernel<<<1, 256, 0, stream>>>(pA, pB, out, npart);
  } else {
    float* b0 = (float*)d_ws;
    float* b1 = b0 + NT;
    double* pA = (double*)(b1 + NT);
    double* pB = pA + 2 * MAXPART;
    const dim3 grd(3, 24, nch * B);
    skel_iter<<<grd, blk, 0, stream>>>(target, b0, pred, pA, nullptr, nullptr, nullptr, nullptr, cz, nch, 0);
    skel_iter<<<grd, blk, 0, stream>>>(b0, b1, pred, pA, nullptr, nullptr, nullptr, nullptr, cz, nch, 0);
    skel_iter<<<grd, blk, 0, stream>>>(b1, b0, pred, pA, nullptr, nullptr, nullptr, nullptr, cz, nch, 0);
    skel_iter<<<grd, blk, 0, stream>>>(b0, b1, pred, pA, nullptr, nullptr, nullptr, nullptr, cz, nch, 0);
    skel_iter<<<grd, blk, 0, stream>>>(b1, b0, pred, pA, nullptr, nullptr, nullptr, nullptr, cz, nch, 1);
    skel_iter<<<grd, blk, 0, stream>>>(pred, b0, target, pB, nullptr, nullptr, nullptr, nullptr, cz, nch, 0);
    skel_iter<<<grd, blk, 0, stream>>>(b0, b1, target, pB, nullptr, nullptr, nullptr, nullptr, cz, nch, 0);
    skel_iter<<<grd, blk, 0, stream>>>(b1, b0, target, pB, nullptr, nullptr, nullptr, nullptr, cz, nch, 0);
    skel_iter<<<grd, blk, 0, stream>>>(b0, b1, target, pB, nullptr, nullptr, nullptr, nullptr, cz, nch, 0);
    skel_iter<<<grd, blk, 0, stream>>>(b1, b0, target, pB, nullptr, nullptr, nullptr, nullptr, cz, nch, 1);
    finalize_kernel<<<1, 256, 0, stream>>>(pA, pB, out, npart);
  }
}

// Round 6
// 517.553 us; speedup vs baseline: 5.6986x; 1.3093x over previous
//
#include <hip/hip_runtime.h>
#include <cfloat>

// ClDiceLoss (B=2, C=1, 192^3) fp32.
// Fused soft-skeletonize iteration, 1-barrier-per-plane pipeline, with all
// LDS traffic vectorized (b64/b128) — round-5 was DS-instruction-issue bound
// (~272 scalar DS instr/block-step ≈ 1414 cyc ≈ measured 139 us).
//   step s (z = z0+s):
//     A: load x(z+1) -> xs[(z+1)&3]  (float2 global, b128 LDS write)
//        M(z-1) = 7pt cross-min -> ms[(z-1)&1]  (float4 cells/thread)
//     barrier
//     B: P(z-1) = 3x3 in-plane max of M(z-1) (3x (b128+b64) reads, float4
//        cells/thread); M(z-1)-center + x(z-1) captured to registers; emit
//        out(z-2) = relu(x - relu(max(P(z-3..z-1)) - M(z-2))) from history.
// Slot disjointness (xs 4-deep, ms parity) keeps A(s+1) race-free vs B(s).
// Boundary: M at out-of-volume (y,x) = -FLT_MAX (exact -inf-pad reduce_window
// semantics); z edges via plane-index guards; clamped x loads harmless (min).
// Both chains in one dispatch when ws allows; 5th iteration fuses reductions.

constexpr int D = 192, H = 192, W = 192, B = 2;
constexpr int HW = H * W;
constexpr int VOL = D * HW;
constexpr int TX = 64, TY = 8;
constexpr int CZ = 32, NCH = 6;
constexpr int MAXPART = 3 * 24 * NCH * B;   // 864 blocks per chain

struct Six { float a0, a1, a2, a3, a4, a5; };
__device__ __forceinline__ Six ld6(const float* p) {
  const float4 u = *(const float4*)p;
  const float2 v = *(const float2*)(p + 4);
  return {u.x, u.y, u.z, u.w, v.x, v.y};
}
__device__ __forceinline__ float max3(float a, float b, float c) {
  return fmaxf(fmaxf(a, b), c);
}

__global__ __launch_bounds__(256, 7) void skel_iter(
    const float* __restrict__ srcA, float* __restrict__ dstA,
    const float* __restrict__ othA, double* __restrict__ partA,
    const float* __restrict__ srcB, float* __restrict__ dstB,
    const float* __restrict__ othB, double* __restrict__ partB,
    int cz, int nch, int last) {
  __shared__ alignas(16) float xs[4][12 * 68];  // x planes, halo 2 (13.1 KB)
  __shared__ alignas(16) float ms[2][10 * 68];  // M parity planes (5.4 KB)
  __shared__ double red[8];

  const int tid = threadIdx.x;
  const int wave = tid >> 6;
  const int lane = tid & 63;
  const int x0 = blockIdx.x * TX;
  const int y0 = blockIdx.y * TY;
  int t = blockIdx.z;
  const int chunk = t % nch; t /= nch;
  const int b = t % B;
  const int chain = t / B;
  const int z0 = chunk * cz;

  const float* vs = (chain ? srcB : srcA) + (size_t)b * VOL;
  float* vd = (chain ? dstB : dstA) + (size_t)b * VOL;
  const float* vo = (chain ? othB : othA) + (size_t)b * VOL;
  double* part = chain ? partB : partA;

  // ---- hoisted z-invariant geometry ----
  // Loader: 204 threads, slot = (row 0..11, quad 0..16); x idx 4q..4q+3.
  const int l_row = tid / 17, l_q = tid - l_row * 17;
  const int l_gy = min(max(y0 - 2 + l_row, 0), H - 1) * W;
  const int l_gx0 = x0 - 2 + 4 * l_q;
  const bool l_d0 = (l_gx0 < 0);            // left-edge pair, clamp-dup
  const bool l_d1 = (l_gx0 + 2 >= W);       // right-edge pair, clamp-dup
  const int l_a0 = l_gy + (l_d0 ? 0 : l_gx0);
  const int l_a1 = l_gy + (l_d1 ? (W - 1) : (l_gx0 + 2));
  const int l_lds = l_row * 68 + 4 * l_q;

  // M: 170 threads, slot = (row 0..9, quad 0..16); M cols c0..c0+3.
  const int m_c0 = 4 * l_q;
  const bool m_rok = ((unsigned)(y0 - 1 + l_row) < (unsigned)H);
  bool m_ok[4];
  #pragma unroll
  for (int i = 0; i < 4; ++i)
    m_ok[i] = m_rok && ((unsigned)(x0 - 1 + m_c0 + i) < (unsigned)W);
  const int m_xc = (l_row + 1) * 68 + m_c0;   // center x row base
  const int m_xu = l_row * 68 + m_c0;
  const int m_xd = (l_row + 2) * 68 + m_c0;
  const int m_o = l_row * 68 + m_c0;

  // B: 128 threads, cell quad (row r 0..7, cols c0..c0+3).
  const int b_r = tid >> 4;
  const int b_c0 = 4 * (tid & 15);
  const int b_m0 = b_r * 68 + b_c0;
  const int b_x = (b_r + 2) * 68 + b_c0 + 2;  // x idx c0+2..c0+5
  const int b_off = (y0 + b_r) * W + x0 + b_c0;

  auto load_x = [&](int z) {
    if (tid < 204) {
      const int zc = min(max(z, 0), D - 1);
      const float* base = vs + (size_t)zc * HW;
      float2 p0, p1;
      if (l_d0) { const float v = base[l_a0]; p0 = {v, v}; }
      else p0 = *(const float2*)(base + l_a0);
      if (l_d1) { const float v = base[l_a1]; p1 = {v, v}; }
      else p1 = *(const float2*)(base + l_a1);
      *(float4*)&xs[(z + 1024) & 3][l_lds] = {p0.x, p0.y, p1.x, p1.y};
    }
  };

  auto m_stage = [&](int z) {   // M(z) -> ms[z&1]
    if (tid < 170) {
      const float* xc = xs[(z + 1024) & 3];
      const float* xm = xs[(z + 1023) & 3];
      const float* xq = xs[(z + 1025) & 3];
      float v[4];
      {
        const Six c = ld6(xc + m_xc);
        v[0] = fminf(fminf(c.a0, c.a1), c.a2);
        v[1] = fminf(fminf(c.a1, c.a2), c.a3);
        v[2] = fminf(fminf(c.a2, c.a3), c.a4);
        v[3] = fminf(fminf(c.a3, c.a4), c.a5);
      }
      {
        const Six u = ld6(xc + m_xu);
        v[0] = fminf(v[0], u.a1); v[1] = fminf(v[1], u.a2);
        v[2] = fminf(v[2], u.a3); v[3] = fminf(v[3], u.a4);
      }
      {
        const Six d = ld6(xc + m_xd);
        v[0] = fminf(v[0], d.a1); v[1] = fminf(v[1], d.a2);
        v[2] = fminf(v[2], d.a3); v[3] = fminf(v[3], d.a4);
      }
      {
        const Six zm = ld6(xm + m_xc);
        v[0] = fminf(v[0], zm.a1); v[1] = fminf(v[1], zm.a2);
        v[2] = fminf(v[2], zm.a3); v[3] = fminf(v[3], zm.a4);
      }
      {
        const Six zq = ld6(xq + m_xc);
        v[0] = fminf(v[0], zq.a1); v[1] = fminf(v[1], zq.a2);
        v[2] = fminf(v[2], zq.a3); v[3] = fminf(v[3], zq.a4);
      }
      const float4 o = {m_ok[0] ? v[0] : -FLT_MAX, m_ok[1] ? v[1] : -FLT_MAX,
                        m_ok[2] ? v[2] : -FLT_MAX, m_ok[3] ? v[3] : -FLT_MAX};
      *(float4*)&ms[z & 1][m_o] = o;
    }
  };

  float p_mm[4], p_m[4], m_prev[4], x_prev[4];
  float sp = 0.0f, ss = 0.0f;

  // Prologue: x planes z0-2..z0.
  load_x(z0 - 2);
  load_x(z0 - 1);
  load_x(z0);
  __syncthreads();

  for (int s = 0; s <= cz + 1; ++s) {
    const int z = z0 + s;
    // ---- phase A ----
    if (s <= cz) load_x(z + 1);
    m_stage(z - 1);
    __syncthreads();
    // ---- phase B ----
    if (tid < 128) {
      const float* mp = ms[(z - 1) & 1];
      float pc[4], mc[4];
      {
        const Six r0 = ld6(mp + b_m0);
        pc[0] = max3(r0.a0, r0.a1, r0.a2);
        pc[1] = max3(r0.a1, r0.a2, r0.a3);
        pc[2] = max3(r0.a2, r0.a3, r0.a4);
        pc[3] = max3(r0.a3, r0.a4, r0.a5);
        const Six r1 = ld6(mp + b_m0 + 68);
        mc[0] = r1.a1; mc[1] = r1.a2; mc[2] = r1.a3; mc[3] = r1.a4;
        pc[0] = fmaxf(pc[0], max3(r1.a0, r1.a1, r1.a2));
        pc[1] = fmaxf(pc[1], max3(r1.a1, r1.a2, r1.a3));
        pc[2] = fmaxf(pc[2], max3(r1.a2, r1.a3, r1.a4));
        pc[3] = fmaxf(pc[3], max3(r1.a3, r1.a4, r1.a5));
        const Six r2 = ld6(mp + b_m0 + 136);
        pc[0] = fmaxf(pc[0], max3(r2.a0, r2.a1, r2.a2));
        pc[1] = fmaxf(pc[1], max3(r2.a1, r2.a2, r2.a3));
        pc[2] = fmaxf(pc[2], max3(r2.a2, r2.a3, r2.a4));
        pc[3] = fmaxf(pc[3], max3(r2.a3, r2.a4, r2.a5));
      }
      const float* xp = xs[(z + 1023) & 3];   // x plane z-1
      const float2 xa = *(const float2*)(xp + b_x);
      const float2 xb = *(const float2*)(xp + b_x + 2);
      const float xc4[4] = {xa.x, xa.y, xb.x, xb.y};
      if (s >= 2) {
        const int zo = z - 2;
        const bool zlo = (zo > 0), zhi = (zo < D - 1);
        float o[4];
        #pragma unroll
        for (int i = 0; i < 4; ++i) {
          float p = p_m[i];
          if (zlo) p = fmaxf(p, p_mm[i]);
          if (zhi) p = fmaxf(p, pc[i]);
          const float contour = fmaxf(p - m_prev[i], 0.0f);
          o[i] = fmaxf(x_prev[i] - contour, 0.0f);
        }
        const size_t g = (size_t)zo * HW + b_off;
        if (last) {
          const float4 w = *(const float4*)(vo + g);
          sp += o[0] * w.x + o[1] * w.y + o[2] * w.z + o[3] * w.w;
          ss += o[0] + o[1] + o[2] + o[3];
        } else {
          *(float4*)(vd + g) = {o[0], o[1], o[2], o[3]};
        }
      }
      #pragma unroll
      for (int i = 0; i < 4; ++i) {
        p_mm[i] = p_m[i];
        p_m[i] = pc[i];
        m_prev[i] = mc[i];
        x_prev[i] = xc4[i];
      }
    }
  }

  if (last) {
    #pragma unroll
    for (int off = 32; off > 0; off >>= 1) {
      sp += __shfl_down(sp, off, 64);
      ss += __shfl_down(ss, off, 64);
    }
    if (lane == 0) {
      red[wave] = (double)sp;
      red[4 + wave] = (double)ss;
    }
    __syncthreads();
    if (tid == 0) {
      const double a = red[0] + red[1] + red[2] + red[3];
      const double s2 = red[4] + red[5] + red[6] + red[7];
      const int lin = ((b * nch + chunk) * 24 + blockIdx.y) * 3 + blockIdx.x;
      part[2 * lin] = a;
      part[2 * lin + 1] = s2;
    }
  }
}

__global__ void finalize_kernel(const double* __restrict__ pa,
                                const double* __restrict__ pb,
                                float* __restrict__ out, int npart) {
  __shared__ double red[4][4];
  double s[4] = {0, 0, 0, 0};
  for (int i = threadIdx.x; i < npart; i += 256) {
    s[0] += pa[2 * i];
    s[1] += pa[2 * i + 1];
    s[2] += pb[2 * i];
    s[3] += pb[2 * i + 1];
  }
  #pragma unroll
  for (int off = 32; off > 0; off >>= 1)
    #pragma unroll
    for (int j = 0; j < 4; ++j) s[j] += __shfl_down(s[j], off, 64);
  const int wave = threadIdx.x >> 6, lane = threadIdx.x & 63;
  if (lane == 0)
    for (int j = 0; j < 4; ++j) red[j][wave] = s[j];
  __syncthreads();
  if (threadIdx.x == 0) {
    double t[4];
    for (int j = 0; j < 4; ++j)
      t[j] = red[j][0] + red[j][1] + red[j][2] + red[j][3];
    const double recall = (t[0] + 1e-12) / (t[1] + 1e-12);
    const double accv = (t[2] + 1e-12) / (t[3] + 1e-12);
    const double cldice = 2.0 * recall * accv / (recall + accv);
    out[0] = (float)(1.0 - cldice);
  }
}

extern "C" void kernel_launch(void* const* d_in, const int* in_sizes, int n_in,
                              void* d_out, int out_size, void* d_ws, size_t ws_size,
                              hipStream_t stream) {
  const float* pred = (const float*)d_in[0];
  const float* target = (const float*)d_in[1];
  float* out = (float*)d_out;
  const size_t NT = (size_t)VOL * B;

  const size_t need_merged = 4 * NT * sizeof(float) + 4 * MAXPART * sizeof(double);
  const dim3 blk(256, 1, 1);
  const int cz = CZ, nch = NCH;
  const int npart = 3 * 24 * nch * B;   // 864 per chain

  if (ws_size >= need_merged) {
    float* a0 = (float*)d_ws;
    float* a1 = a0 + NT;
    float* c0 = a1 + NT;
    float* c1 = c0 + NT;
    double* pA = (double*)(c1 + NT);
    double* pB = pA + 2 * MAXPART;
    const dim3 grd(3, 24, nch * B * 2);   // 1728 blocks
    skel_iter<<<grd, blk, 0, stream>>>(target, a0, pred, pA, pred, c0, target, pB, cz, nch, 0);
    skel_iter<<<grd, blk, 0, stream>>>(a0, a1, pred, pA, c0, c1, target, pB, cz, nch, 0);
    skel_iter<<<grd, blk, 0, stream>>>(a1, a0, pred, pA, c1, c0, target, pB, cz, nch, 0);
    skel_iter<<<grd, blk, 0, stream>>>(a0, a1, pred, pA, c0, c1, target, pB, cz, nch, 0);
    skel_iter<<<grd, blk, 0, stream>>>(a1, a0, pred, pA, c1, c0, target, pB, cz, nch, 1);
    finalize_kernel<<<1, 256, 0, stream>>>(pA, pB, out, npart);
  } else {
    float* b0 = (float*)d_ws;
    float* b1 = b0 + NT;
    double* pA = (double*)(b1 + NT);
    double* pB = pA + 2 * MAXPART;
    const dim3 grd(3, 24, nch * B);
    skel_iter<<<grd, blk, 0, stream>>>(target, b0, pred, pA, nullptr, nullptr, nullptr, nullptr, cz, nch, 0);
    skel_iter<<<grd, blk, 0, stream>>>(b0, b1, pred, pA, nullptr, nullptr, nullptr, nullptr, cz, nch, 0);
    skel_iter<<<grd, blk, 0, stream>>>(b1, b0, pred, pA, nullptr, nullptr, nullptr, nullptr, cz, nch, 0);
    skel_iter<<<grd, blk, 0, stream>>>(b0, b1, pred, pA, nullptr, nullptr, nullptr, nullptr, cz, nch, 0);
    skel_iter<<<grd, blk, 0, stream>>>(b1, b0, pred, pA, nullptr, nullptr, nullptr, nullptr, cz, nch, 1);
    skel_iter<<<grd, blk, 0, stream>>>(pred, b0, target, pB, nullptr, nullptr, nullptr, nullptr, cz, nch, 0);
    skel_iter<<<grd, blk, 0, stream>>>(b0, b1, target, pB, nullptr, nullptr, nullptr, nullptr, cz, nch, 0);
    skel_iter<<<grd, blk, 0, stream>>>(b1, b0, target, pB, nullptr, nullptr, nullptr, nullptr, cz, nch, 0);
    skel_iter<<<grd, blk, 0, stream>>>(b0, b1, target, pB, nullptr, nullptr, nullptr, nullptr, cz, nch, 0);
    skel_iter<<<grd, blk, 0, stream>>>(b1, b0, target, pB, nullptr, nullptr, nullptr, nullptr, cz, nch, 1);
    finalize_kernel<<<1, 256, 0, stream>>>(pA, pB, out, npart);
  }
}

// Round 7
// 515.335 us; speedup vs baseline: 5.7231x; 1.0043x over previous
//
#include <hip/hip_runtime.h>
#include <cfloat>

// ClDiceLoss (B=2, C=1, 192^3) fp32.
// Fused soft-skeletonize iteration, 1-barrier-per-plane pipeline.
// Round-7: ALL LDS reads are aligned ds_read_b128 (the round-6 b64-at-16B-
// stride halves of ld6 were the 2.07e7 bank-conflict source: lanes l and l+8
// hit the same half-bank set at different addresses). 8-float spans = 2
// aligned b128 whose block addresses are lane-consecutive (17 threads/row ==
// 17 blocks/row for stride-68 arrays -> block = tid + const, the measured
// conflict-free pattern).
//   step s (z = z0+s):
//     A: load x(z+1) -> xs[(z+1)&3]  (float2 global, b128 LDS write)
//        M(z-1) = 7pt cross-min -> ms[(z-1)&1]  (float4 cells/thread)
//     barrier
//     B: P(z-1) = 3x3 in-plane max of M(z-1); M-center + x(z-1) to registers;
//        emit out(z-2) = relu(x - relu(max(P(z-3..z-1)) - M(z-2))) from history.
// Boundary: M at out-of-volume (y,x) = -FLT_MAX (exact -inf-pad reduce_window
// semantics); z edges via plane-index guards; clamped x loads harmless (min).
// Both chains in one dispatch when ws allows; 5th iteration fuses reductions.

constexpr int D = 192, H = 192, W = 192, B = 2;
constexpr int HW = H * W;
constexpr int VOL = D * HW;
constexpr int TX = 64, TY = 8;
constexpr int CZ = 32, NCH = 6;
constexpr int MAXPART = 3 * 24 * NCH * B;   // 864 blocks per chain

struct Eight { float a[8]; };
__device__ __forceinline__ Eight ld8(const float* p) {  // p 16B-aligned
  Eight e;
  const float4 u = *(const float4*)p;
  const float4 v = *(const float4*)(p + 4);
  e.a[0] = u.x; e.a[1] = u.y; e.a[2] = u.z; e.a[3] = u.w;
  e.a[4] = v.x; e.a[5] = v.y; e.a[6] = v.z; e.a[7] = v.w;
  return e;
}
__device__ __forceinline__ float max3(float a, float b, float c) {
  return fmaxf(fmaxf(a, b), c);
}

__global__ __launch_bounds__(256, 7) void skel_iter(
    const float* __restrict__ srcA, float* __restrict__ dstA,
    const float* __restrict__ othA, double* __restrict__ partA,
    const float* __restrict__ srcB, float* __restrict__ dstB,
    const float* __restrict__ othB, double* __restrict__ partB,
    int cz, int nch, int last) {
  __shared__ alignas(16) float xs[4][12 * 68];  // x planes, halo 2 (13.1 KB)
  __shared__ alignas(16) float ms[2][10 * 68];  // M parity planes (5.4 KB)
  __shared__ double red[8];

  const int tid = threadIdx.x;
  const int wave = tid >> 6;
  const int lane = tid & 63;
  const int x0 = blockIdx.x * TX;
  const int y0 = blockIdx.y * TY;
  int t = blockIdx.z;
  const int chunk = t % nch; t /= nch;
  const int b = t % B;
  const int chain = t / B;
  const int z0 = chunk * cz;

  const float* vs = (chain ? srcB : srcA) + (size_t)b * VOL;
  float* vd = (chain ? dstB : dstA) + (size_t)b * VOL;
  const float* vo = (chain ? othB : othA) + (size_t)b * VOL;
  double* part = chain ? partB : partA;

  // ---- hoisted z-invariant geometry ----
  // Loader: 204 threads, slot = (row 0..11, quad 0..16); x idx 4q..4q+3.
  const int l_row = tid / 17, l_q = tid - l_row * 17;
  const int l_gy = min(max(y0 - 2 + l_row, 0), H - 1) * W;
  const int l_gx0 = x0 - 2 + 4 * l_q;
  const bool l_d0 = (l_gx0 < 0);            // left-edge pair, clamp-dup
  const bool l_d1 = (l_gx0 + 2 >= W);       // right-edge pair, clamp-dup
  const int l_a0 = l_gy + (l_d0 ? 0 : l_gx0);
  const int l_a1 = l_gy + (l_d1 ? (W - 1) : (l_gx0 + 2));
  const int l_lds = l_row * 68 + 4 * l_q;

  // M: 170 threads, slot = (row 0..9, quad 0..16); M cols c0..c0+3.
  const int m_c0 = 4 * l_q;
  const bool m_rok = ((unsigned)(y0 - 1 + l_row) < (unsigned)H);
  bool m_ok[4];
  #pragma unroll
  for (int i = 0; i < 4; ++i)
    m_ok[i] = m_rok && ((unsigned)(x0 - 1 + m_c0 + i) < (unsigned)W);
  const int m_xc = (l_row + 1) * 68 + m_c0;   // center x row base (4-aligned)
  const int m_xu = l_row * 68 + m_c0;
  const int m_xd = (l_row + 2) * 68 + m_c0;
  const int m_o = l_row * 68 + m_c0;

  // B: 128 threads, cell quad (row r 0..7, cols c0..c0+3).
  const int b_r = tid >> 4;
  const int b_c0 = 4 * (tid & 15);
  const int b_m0 = b_r * 68 + b_c0;
  const int b_x4 = (b_r + 2) * 68 + b_c0;     // aligned; x cells at elems 2..5
  const int b_off = (y0 + b_r) * W + x0 + b_c0;

  auto load_x = [&](int z) {
    if (tid < 204) {
      const int zc = min(max(z, 0), D - 1);
      const float* base = vs + (size_t)zc * HW;
      float2 p0, p1;
      if (l_d0) { const float v = base[l_a0]; p0 = {v, v}; }
      else p0 = *(const float2*)(base + l_a0);
      if (l_d1) { const float v = base[l_a1]; p1 = {v, v}; }
      else p1 = *(const float2*)(base + l_a1);
      *(float4*)&xs[(z + 1024) & 3][l_lds] = {p0.x, p0.y, p1.x, p1.y};
    }
  };

  auto m_stage = [&](int z) {   // M(z) -> ms[z&1]
    if (tid < 170) {
      const float* xc = xs[(z + 1024) & 3];
      const float* xm = xs[(z + 1023) & 3];
      const float* xq = xs[(z + 1025) & 3];
      float v[4];
      {
        const Eight c = ld8(xc + m_xc);
        #pragma unroll
        for (int i = 0; i < 4; ++i)
          v[i] = fminf(fminf(c.a[i], c.a[i + 1]), c.a[i + 2]);
      }
      {
        const Eight u = ld8(xc + m_xu);
        #pragma unroll
        for (int i = 0; i < 4; ++i) v[i] = fminf(v[i], u.a[i + 1]);
      }
      {
        const Eight d = ld8(xc + m_xd);
        #pragma unroll
        for (int i = 0; i < 4; ++i) v[i] = fminf(v[i], d.a[i + 1]);
      }
      {
        const Eight zm = ld8(xm + m_xc);
        #pragma unroll
        for (int i = 0; i < 4; ++i) v[i] = fminf(v[i], zm.a[i + 1]);
      }
      {
        const Eight zq = ld8(xq + m_xc);
        #pragma unroll
        for (int i = 0; i < 4; ++i) v[i] = fminf(v[i], zq.a[i + 1]);
      }
      const float4 o = {m_ok[0] ? v[0] : -FLT_MAX, m_ok[1] ? v[1] : -FLT_MAX,
                        m_ok[2] ? v[2] : -FLT_MAX, m_ok[3] ? v[3] : -FLT_MAX};
      *(float4*)&ms[z & 1][m_o] = o;
    }
  };

  float p_mm[4], p_m[4], m_prev[4], x_prev[4];
  float sp = 0.0f, ss = 0.0f;

  // Prologue: x planes z0-2..z0.
  load_x(z0 - 2);
  load_x(z0 - 1);
  load_x(z0);
  __syncthreads();

  for (int s = 0; s <= cz + 1; ++s) {
    const int z = z0 + s;
    // ---- phase A ----
    if (s <= cz) load_x(z + 1);
    m_stage(z - 1);
    __syncthreads();
    // ---- phase B ----
    if (tid < 128) {
      const float* mp = ms[(z - 1) & 1];
      float pc[4], mc[4];
      {
        const Eight r0 = ld8(mp + b_m0);
        #pragma unroll
        for (int i = 0; i < 4; ++i)
          pc[i] = max3(r0.a[i], r0.a[i + 1], r0.a[i + 2]);
        const Eight r1 = ld8(mp + b_m0 + 68);
        #pragma unroll
        for (int i = 0; i < 4; ++i) {
          mc[i] = r1.a[i + 1];
          pc[i] = fmaxf(pc[i], max3(r1.a[i], r1.a[i + 1], r1.a[i + 2]));
        }
        const Eight r2 = ld8(mp + b_m0 + 136);
        #pragma unroll
        for (int i = 0; i < 4; ++i)
          pc[i] = fmaxf(pc[i], max3(r2.a[i], r2.a[i + 1], r2.a[i + 2]));
      }
      const Eight xv = ld8(xs[(z + 1023) & 3] + b_x4);  // x plane z-1
      if (s >= 2) {
        const int zo = z - 2;
        const bool zlo = (zo > 0), zhi = (zo < D - 1);
        float o[4];
        #pragma unroll
        for (int i = 0; i < 4; ++i) {
          float p = p_m[i];
          if (zlo) p = fmaxf(p, p_mm[i]);
          if (zhi) p = fmaxf(p, pc[i]);
          const float contour = fmaxf(p - m_prev[i], 0.0f);
          o[i] = fmaxf(x_prev[i] - contour, 0.0f);
        }
        const size_t g = (size_t)zo * HW + b_off;
        if (last) {
          const float4 w = *(const float4*)(vo + g);
          sp += o[0] * w.x + o[1] * w.y + o[2] * w.z + o[3] * w.w;
          ss += o[0] + o[1] + o[2] + o[3];
        } else {
          *(float4*)(vd + g) = {o[0], o[1], o[2], o[3]};
        }
      }
      #pragma unroll
      for (int i = 0; i < 4; ++i) {
        p_mm[i] = p_m[i];
        p_m[i] = pc[i];
        m_prev[i] = mc[i];
        x_prev[i] = xv.a[i + 2];
      }
    }
  }

  if (last) {
    #pragma unroll
    for (int off = 32; off > 0; off >>= 1) {
      sp += __shfl_down(sp, off, 64);
      ss += __shfl_down(ss, off, 64);
    }
    if (lane == 0) {
      red[wave] = (double)sp;
      red[4 + wave] = (double)ss;
    }
    __syncthreads();
    if (tid == 0) {
      const double a = red[0] + red[1] + red[2] + red[3];
      const double s2 = red[4] + red[5] + red[6] + red[7];
      const int lin = ((b * nch + chunk) * 24 + blockIdx.y) * 3 + blockIdx.x;
      part[2 * lin] = a;
      part[2 * lin + 1] = s2;
    }
  }
}

__global__ void finalize_kernel(const double* __restrict__ pa,
                                const double* __restrict__ pb,
                                float* __restrict__ out, int npart) {
  __shared__ double red[4][4];
  double s[4] = {0, 0, 0, 0};
  for (int i = threadIdx.x; i < npart; i += 256) {
    s[0] += pa[2 * i];
    s[1] += pa[2 * i + 1];
    s[2] += pb[2 * i];
    s[3] += pb[2 * i + 1];
  }
  #pragma unroll
  for (int off = 32; off > 0; off >>= 1)
    #pragma unroll
    for (int j = 0; j < 4; ++j) s[j] += __shfl_down(s[j], off, 64);
  const int wave = threadIdx.x >> 6, lane = threadIdx.x & 63;
  if (lane == 0)
    for (int j = 0; j < 4; ++j) red[j][wave] = s[j];
  __syncthreads();
  if (threadIdx.x == 0) {
    double t[4];
    for (int j = 0; j < 4; ++j)
      t[j] = red[j][0] + red[j][1] + red[j][2] + red[j][3];
    const double recall = (t[0] + 1e-12) / (t[1] + 1e-12);
    const double accv = (t[2] + 1e-12) / (t[3] + 1e-12);
    const double cldice = 2.0 * recall * accv / (recall + accv);
    out[0] = (float)(1.0 - cldice);
  }
}

extern "C" void kernel_launch(void* const* d_in, const int* in_sizes, int n_in,
                              void* d_out, int out_size, void* d_ws, size_t ws_size,
                              hipStream_t stream) {
  const float* pred = (const float*)d_in[0];
  const float* target = (const float*)d_in[1];
  float* out = (float*)d_out;
  const size_t NT = (size_t)VOL * B;

  const size_t need_merged = 4 * NT * sizeof(float) + 4 * MAXPART * sizeof(double);
  const dim3 blk(256, 1, 1);
  const int cz = CZ, nch = NCH;
  const int npart = 3 * 24 * nch * B;   // 864 per chain

  if (ws_size >= need_merged) {
    float* a0 = (float*)d_ws;
    float* a1 = a0 + NT;
    float* c0 = a1 + NT;
    float* c1 = c0 + NT;
    double* pA = (double*)(c1 + NT);
    double* pB = pA + 2 * MAXPART;
    const dim3 grd(3, 24, nch * B * 2);   // 1728 blocks
    skel_iter<<<grd, blk, 0, stream>>>(target, a0, pred, pA, pred, c0, target, pB, cz, nch, 0);
    skel_iter<<<grd, blk, 0, stream>>>(a0, a1, pred, pA, c0, c1, target, pB, cz, nch, 0);
    skel_iter<<<grd, blk, 0, stream>>>(a1, a0, pred, pA, c1, c0, target, pB, cz, nch, 0);
    skel_iter<<<grd, blk, 0, stream>>>(a0, a1, pred, pA, c0, c1, target, pB, cz, nch, 0);
    skel_iter<<<grd, blk, 0, stream>>>(a1, a0, pred, pA, c1, c0, target, pB, cz, nch, 1);
    finalize_kernel<<<1, 256, 0, stream>>>(pA, pB, out, npart);
  } else {
    float* b0 = (float*)d_ws;
    float* b1 = b0 + NT;
    double* pA = (double*)(b1 + NT);
    double* pB = pA + 2 * MAXPART;
    const dim3 grd(3, 24, nch * B);
    skel_iter<<<grd, blk, 0, stream>>>(target, b0, pred, pA, nullptr, nullptr, nullptr, nullptr, cz, nch, 0);
    skel_iter<<<grd, blk, 0, stream>>>(b0, b1, pred, pA, nullptr, nullptr, nullptr, nullptr, cz, nch, 0);
    skel_iter<<<grd, blk, 0, stream>>>(b1, b0, pred, pA, nullptr, nullptr, nullptr, nullptr, cz, nch, 0);
    skel_iter<<<grd, blk, 0, stream>>>(b0, b1, pred, pA, nullptr, nullptr, nullptr, nullptr, cz, nch, 0);
    skel_iter<<<grd, blk, 0, stream>>>(b1, b0, pred, pA, nullptr, nullptr, nullptr, nullptr, cz, nch, 1);
    skel_iter<<<grd, blk, 0, stream>>>(pred, b0, target, pB, nullptr, nullptr, nullptr, nullptr, cz, nch, 0);
    skel_iter<<<grd, blk, 0, stream>>>(b0, b1, target, pB, nullptr, nullptr, nullptr, nullptr, cz, nch, 0);
    skel_iter<<<grd, blk, 0, stream>>>(b1, b0, target, pB, nullptr, nullptr, nullptr, nullptr, cz, nch, 0);
    skel_iter<<<grd, blk, 0, stream>>>(b0, b1, target, pB, nullptr, nullptr, nullptr, nullptr, cz, nch, 0);
    skel_iter<<<grd, blk, 0, stream>>>(b1, b0, target, pB, nullptr, nullptr, nullptr, nullptr, cz, nch, 1);
    finalize_kernel<<<1, 256, 0, stream>>>(pA, pB, out, npart);
  }
}